// Round 2
// baseline (32817.661 us; speedup 1.0000x reference)
//
#include <hip/hip_runtime.h>
#include <hip/hip_bf16.h>
#include <math.h>

#define Bb 64
#define Tt 512
#define Ii 1024
#define Hh 2048

// ---------------------------------------------------------------------------
// Kernel 1: x_proj = input @ w_ih^T + b_ih -> written into outs region.
// 128x128 tile, BK=32, 8x8 per thread, k-major LDS. VALU-bound fp32 GEMM.
// ---------------------------------------------------------------------------
__global__ __launch_bounds__(256, 2) void xproj_kernel(
    const float* __restrict__ A,     // [32768][1024]
    const float* __restrict__ W,     // [2048][1024]
    const float* __restrict__ bias,  // [2048]
    float* __restrict__ out)         // [32768][2048]
{
    constexpr int BK = 32, K = Ii, N = Hh;
    __shared__ float As[BK][128];
    __shared__ float Ws[BK][128];

    const int tid  = threadIdx.x;
    const int m0   = blockIdx.y * 128;
    const int n0   = blockIdx.x * 128;
    const int tx   = tid & 15;       // 8 cols each
    const int ty   = tid >> 4;       // 8 rows each
    const int srow = tid >> 1;       // staging row 0..127
    const int sk0  = (tid & 1) * 4;  // staging f4 slots sk0..sk0+3

    float acc[8][8] = {};
    const float* aptr = A + (size_t)(m0 + srow) * K + sk0 * 4;
    const float* wptr = W + (size_t)(n0 + srow) * K + sk0 * 4;

    for (int k0 = 0; k0 < K; k0 += BK) {
        #pragma unroll
        for (int i = 0; i < 4; ++i) {
            float4 va = *(const float4*)(aptr + k0 + i * 4);
            As[(sk0 + i) * 4 + 0][srow] = va.x;
            As[(sk0 + i) * 4 + 1][srow] = va.y;
            As[(sk0 + i) * 4 + 2][srow] = va.z;
            As[(sk0 + i) * 4 + 3][srow] = va.w;
            float4 vw = *(const float4*)(wptr + k0 + i * 4);
            Ws[(sk0 + i) * 4 + 0][srow] = vw.x;
            Ws[(sk0 + i) * 4 + 1][srow] = vw.y;
            Ws[(sk0 + i) * 4 + 2][srow] = vw.z;
            Ws[(sk0 + i) * 4 + 3][srow] = vw.w;
        }
        __syncthreads();
        #pragma unroll
        for (int kk = 0; kk < BK; ++kk) {
            float4 a0 = *(const float4*)&As[kk][ty * 8];
            float4 a1 = *(const float4*)&As[kk][ty * 8 + 4];
            float4 w0 = *(const float4*)&Ws[kk][tx * 8];
            float4 w1 = *(const float4*)&Ws[kk][tx * 8 + 4];
            float av[8] = {a0.x, a0.y, a0.z, a0.w, a1.x, a1.y, a1.z, a1.w};
            float wv[8] = {w0.x, w0.y, w0.z, w0.w, w1.x, w1.y, w1.z, w1.w};
            #pragma unroll
            for (int i2 = 0; i2 < 8; ++i2)
                #pragma unroll
                for (int j2 = 0; j2 < 8; ++j2)
                    acc[i2][j2] += av[i2] * wv[j2];
        }
        __syncthreads();
    }

    const float4 b0 = *(const float4*)(bias + n0 + tx * 8);
    const float4 b1 = *(const float4*)(bias + n0 + tx * 8 + 4);
    #pragma unroll
    for (int r = 0; r < 8; ++r) {
        const size_t m = m0 + ty * 8 + r;
        float4 o0 = {acc[r][0] + b0.x, acc[r][1] + b0.y, acc[r][2] + b0.z, acc[r][3] + b0.w};
        float4 o1 = {acc[r][4] + b1.x, acc[r][5] + b1.y, acc[r][6] + b1.z, acc[r][7] + b1.w};
        *(float4*)(out + m * N + n0 + tx * 8)     = o0;
        *(float4*)(out + m * N + n0 + tx * 8 + 4) = o1;
    }
}

// ---------------------------------------------------------------------------
// Kernel 2: one recurrence step, restructured.
// Grid 256 WGs x 256 thr. WG = (BG in 0..1 -> 32 batches) x (CG in 0..127 -> 16 cols).
// Threads: ks(16 k-split) x bgl(4) x wave(4); wave = bhi + 2*cg8.
// Thread register tile: rB=4 rows {bg,bg+8,bg+16,bg+24} x rC=8 cols, 128 k each.
// h staged global->LDS in 256-k chunks, double-buffered, XOR slot swizzle.
// w read directly from global (L2/L3 resident), coalesced across ks lanes.
// k-partials reduced through LDS scratch; epilogue fuses xp+noise+bias+tanh.
// ---------------------------------------------------------------------------
__global__ __launch_bounds__(256, 1) void step_kernel(
    const float* __restrict__ w_hh,     // [H][H]
    const float* __restrict__ b_hh,     // [H]
    const float* __restrict__ internal, // [B][T]
    const float* __restrict__ h0,       // [B][H]
    float* __restrict__ out,            // [B][T][H] ++ [B][H]
    const int t)
{
    __shared__ float4 Hs[2][32][64];    // 64 KiB, [buf][row][f4slot]; content swizzled

    const int tid = threadIdx.x;
    const int ks  = tid & 15;
    const int bgl = (tid >> 4) & 3;
    const int wv  = tid >> 6;
    const int bhi = wv & 1;
    const int cg8 = wv >> 1;
    const int bg  = bgl + 4 * bhi;       // 0..7
    const int BG  = blockIdx.x & 1;
    const int CG  = blockIdx.x >> 1;

    const int col0 = CG * 16 + cg8 * 8;
    const float* wbase = w_hh + (size_t)col0 * Hh;

    const size_t hstride = (t == 0) ? (size_t)Hh : (size_t)Tt * Hh;
    const float* hsrc = (t == 0) ? h0 : (out + (size_t)(t - 1) * Hh);

    float acc[4][8];
    #pragma unroll
    for (int i = 0; i < 4; ++i)
        #pragma unroll
        for (int j = 0; j < 8; ++j) acc[i][j] = 0.f;

    const int sig = tid & 63;            // staging f4 slot
    float4 stg[8];

    // prologue: stage chunk 0 into buf 0
    #pragma unroll
    for (int p = 0; p < 8; ++p) {
        const int r = 4 * p + wv;
        stg[p] = *(const float4*)(hsrc + (size_t)(BG * 32 + r) * hstride
                                  + 4 * (sig ^ (r & 7)));
    }
    #pragma unroll
    for (int p = 0; p < 8; ++p) {
        const int r = 4 * p + wv;
        Hs[0][r][sig] = stg[p];
    }

    for (int c = 0; c < 8; ++c) {
        __syncthreads();                  // chunk c staged & visible
        // issue next chunk's loads early (latency hides under compute)
        if (c < 7) {
            #pragma unroll
            for (int p = 0; p < 8; ++p) {
                const int r = 4 * p + wv;
                stg[p] = *(const float4*)(hsrc + (size_t)(BG * 32 + r) * hstride
                                          + (c + 1) * 256 + 4 * (sig ^ (r & 7)));
            }
        }
        // compute chunk c
        const float4* hbuf = &Hs[c & 1][0][0];
        const float* wc = wbase + c * 256;
        #pragma unroll
        for (int q = 0; q < 4; ++q) {
            const int s_in = q * 16 + ks;       // in-chunk f4 slot
            const int sswz = s_in ^ bg;         // row&7 == bg for all 4 rows
            float4 hv[4];
            #pragma unroll
            for (int i = 0; i < 4; ++i)
                hv[i] = hbuf[(bg + 8 * i) * 64 + sswz];
            float4 wvv[8];
            #pragma unroll
            for (int j = 0; j < 8; ++j)
                wvv[j] = *(const float4*)(wc + (size_t)j * Hh + 4 * s_in);
            #pragma unroll
            for (int i = 0; i < 4; ++i) {
                #pragma unroll
                for (int j = 0; j < 8; ++j) {
                    acc[i][j] += hv[i].x * wvv[j].x;
                    acc[i][j] += hv[i].y * wvv[j].y;
                    acc[i][j] += hv[i].z * wvv[j].z;
                    acc[i][j] += hv[i].w * wvv[j].w;
                }
            }
        }
        // write staged regs for chunk c+1 (data arrived during compute)
        if (c < 7) {
            #pragma unroll
            for (int p = 0; p < 8; ++p) {
                const int r = 4 * p + wv;
                Hs[(c + 1) & 1][r][sig] = stg[p];
            }
        }
    }

    // ---- k-split reduce via LDS scratch (reuses buf 0: 32 KiB) ----
    float* scratch = (float*)&Hs[0][0][0];    // [256][32]
    #pragma unroll
    for (int i = 0; i < 4; ++i) {
        float4 s0 = {acc[i][0], acc[i][1], acc[i][2], acc[i][3]};
        float4 s1 = {acc[i][4], acc[i][5], acc[i][6], acc[i][7]};
        *(float4*)&scratch[tid * 32 + i * 8]     = s0;
        *(float4*)&scratch[tid * 32 + i * 8 + 4] = s1;
    }
    __syncthreads();

    // each thread finalizes outputs o = 2*tid, 2*tid+1
    #pragma unroll
    for (int e = 0; e < 2; ++e) {
        const int o    = tid * 2 + e;
        const int jj   = o & 7;
        const int c8   = (o >> 3) & 1;
        const int io   = (o >> 4) & 3;
        const int bgo  = o >> 6;                 // 0..7
        const int rloc = bgo + 8 * io;
        const int rowg = BG * 32 + rloc;
        const int colg = CG * 16 + c8 * 8 + jj;
        const int tbase = 16 * (bgo & 3) + 64 * ((bgo >> 2) + 2 * c8);
        const int slotf = io * 8 + jj;
        float s = 0.f;
        #pragma unroll
        for (int kk = 0; kk < 16; ++kk)
            s += scratch[(tbase + kk) * 32 + slotf];
        const size_t obase = (size_t)rowg * Tt * Hh + (size_t)t * Hh + colg;
        const float xp = out[obase];
        const float nz = internal[rowg * Tt + t];
        const float g  = tanhf(xp + nz + b_hh[colg] + s);
        out[obase] = g;
        if (t == Tt - 1)
            out[(size_t)Bb * Tt * Hh + (size_t)rowg * Hh + colg] = g;
    }
}

// ---------------------------------------------------------------------------
extern "C" void kernel_launch(void* const* d_in, const int* in_sizes, int n_in,
                              void* d_out, int out_size, void* d_ws, size_t ws_size,
                              hipStream_t stream) {
    const float* input    = (const float*)d_in[0];
    const float* internal = (const float*)d_in[1];
    const float* w_ih     = (const float*)d_in[2];
    const float* w_hh     = (const float*)d_in[3];
    const float* b_ih     = (const float*)d_in[4];
    const float* b_hh     = (const float*)d_in[5];
    const float* h0       = (const float*)d_in[6];
    float* out = (float*)d_out;

    dim3 g1(Hh / 128, (Bb * Tt) / 128);   // 16 x 256
    hipLaunchKernelGGL(xproj_kernel, g1, dim3(256), 0, stream,
                       input, w_ih, b_ih, out);

    for (int t = 0; t < Tt; ++t) {
        hipLaunchKernelGGL(step_kernel, dim3(256), dim3(256), 0, stream,
                           w_hh, b_hh, internal, h0, out, t);
    }
}

// Round 3
// 5574.029 us; speedup vs baseline: 5.8876x; 5.8876x over previous
//
#include <hip/hip_runtime.h>
#include <hip/hip_bf16.h>
#include <math.h>

#define Bb 64
#define Tt 512
#define Ii 1024
#define Hh 2048

typedef __attribute__((ext_vector_type(8))) short bf16x8;
typedef __attribute__((ext_vector_type(8))) unsigned short ushort8;
typedef __attribute__((ext_vector_type(4))) float f32x4;

__device__ __forceinline__ unsigned short f2bf(float x) {
    unsigned int u = __float_as_uint(x);
    unsigned int r = u + 0x7fffu + ((u >> 16) & 1u);
    return (unsigned short)(r >> 16);
}

// ---------------------------------------------------------------------------
// Convert fp32 -> bf16 (raw ushort bits), 4 elems/thread.
// ---------------------------------------------------------------------------
__global__ __launch_bounds__(256) void cvt_kernel(
    const float* __restrict__ src, unsigned short* __restrict__ dst)
{
    const int i = (blockIdx.x * 256 + threadIdx.x) * 4;
    float4 v = *(const float4*)(src + i);
    ushort4 o;
    o.x = f2bf(v.x); o.y = f2bf(v.y); o.z = f2bf(v.z); o.w = f2bf(v.w);
    *(ushort4*)(dst + i) = o;
}

// ---------------------------------------------------------------------------
// xproj: out[M=B*T][N=H] = input[M][K=I] @ w_ih^T + b_ih   (bf16 MFMA)
// 128x128 tile, BK=32, 4 waves (2x2 quadrants of 64x64), 16x16x32 MFMA.
// A converted fp32->bf16 on the fly while staging to LDS.
// LDS rows padded to 40 ushorts (80 B) -> <=2-way bank aliasing on frag reads.
// ---------------------------------------------------------------------------
__global__ __launch_bounds__(256, 2) void xproj_kernel(
    const float* __restrict__ A,              // input [32768][1024] fp32
    const unsigned short* __restrict__ Wbf,   // w_ih bf16 [2048][1024]
    const float* __restrict__ bias,           // b_ih [2048]
    float* __restrict__ out)                  // [32768][2048] fp32
{
    __shared__ unsigned short As[128 * 40];
    __shared__ unsigned short Bs[128 * 40];

    const int tid  = threadIdx.x;
    const int lane = tid & 63;
    const int wid  = tid >> 6;
    const int wm   = wid & 1;        // 0..1 row-quadrant
    const int wn   = wid >> 1;       // 0..1 col-quadrant
    const int rlo  = lane & 15;
    const int khi  = lane >> 4;      // 0..3

    const int m0 = blockIdx.y * 128;
    const int n0 = blockIdx.x * 128;

    f32x4 acc[4][4];
    #pragma unroll
    for (int i = 0; i < 4; ++i)
        #pragma unroll
        for (int j = 0; j < 4; ++j) acc[i][j] = (f32x4)0.f;

    for (int k0 = 0; k0 < Ii; k0 += 32) {
        // stage A: 128 rows x 32 k fp32 -> bf16. 4 passes, 4 fp32/thread.
        #pragma unroll
        for (int p = 0; p < 4; ++p) {
            const int flat = p * 256 + tid;
            const int row  = flat >> 3;
            const int c4   = flat & 7;
            float4 v = *(const float4*)(A + (size_t)(m0 + row) * Ii + k0 + c4 * 4);
            ushort4 o;
            o.x = f2bf(v.x); o.y = f2bf(v.y); o.z = f2bf(v.z); o.w = f2bf(v.w);
            *(ushort4*)(As + row * 40 + c4 * 4) = o;
        }
        // stage B: 128 rows x 32 k bf16. 2 passes, 8 ushort/thread.
        #pragma unroll
        for (int p = 0; p < 2; ++p) {
            const int flat = p * 256 + tid;
            const int row  = flat >> 2;
            const int c8   = flat & 3;
            ushort8 v = *(const ushort8*)(Wbf + (size_t)(n0 + row) * Ii + k0 + c8 * 8);
            *(ushort8*)(Bs + row * 40 + c8 * 8) = v;
        }
        __syncthreads();

        bf16x8 af[4], bf[4];
        #pragma unroll
        for (int i = 0; i < 4; ++i)
            af[i] = *(const bf16x8*)(As + (wm * 64 + i * 16 + rlo) * 40 + khi * 8);
        #pragma unroll
        for (int j = 0; j < 4; ++j)
            bf[j] = *(const bf16x8*)(Bs + (wn * 64 + j * 16 + rlo) * 40 + khi * 8);
        #pragma unroll
        for (int i = 0; i < 4; ++i)
            #pragma unroll
            for (int j = 0; j < 4; ++j)
                acc[i][j] = __builtin_amdgcn_mfma_f32_16x16x32_bf16(
                    af[i], bf[j], acc[i][j], 0, 0, 0);
        __syncthreads();
    }

    // epilogue: C layout col = lane&15, row = (lane>>4)*4 + reg
    #pragma unroll
    for (int j = 0; j < 4; ++j) {
        const int col = n0 + wn * 64 + j * 16 + rlo;
        const float bj = bias[col];
        #pragma unroll
        for (int i = 0; i < 4; ++i) {
            #pragma unroll
            for (int r = 0; r < 4; ++r) {
                const int m = m0 + wm * 64 + i * 16 + khi * 4 + r;
                out[(size_t)m * Hh + col] = acc[i][j][r] + bj;
            }
        }
    }
}

// ---------------------------------------------------------------------------
// One recurrence step via MFMA.
// 256 WGs x 256 thr (4 waves). flatwave fw = blockIdx*4 + wid:
//   ks = fw&1 (K half), mtile = (fw>>1)&3 (16 batch rows), ntile = fw>>3 (16 cols).
// Wave: 16x16 tile over K=1024: 32 MFMA, A/B frags loaded straight from
// global (L2-resident), 4 independent acc chains. k-split pair reduces via LDS.
// Epilogue fuses xp + internal + b_hh + tanh; writes fp32 out and bf16 h_nxt.
// ---------------------------------------------------------------------------
__global__ __launch_bounds__(256, 1) void step_mfma(
    const unsigned short* __restrict__ w_bf,   // [2048][2048] bf16
    const unsigned short* __restrict__ h_cur,  // [64][2048] bf16
    unsigned short* __restrict__ h_nxt,        // [64][2048] bf16
    const float* __restrict__ b_hh,
    const float* __restrict__ internal,        // [64][512]
    float* __restrict__ out,                   // [B][T][H] ++ [B][H]
    const int t)
{
    __shared__ f32x4 red[2][64];

    const int tid  = threadIdx.x;
    const int lane = tid & 63;
    const int wid  = tid >> 6;
    const int fw   = blockIdx.x * 4 + wid;
    const int ks   = fw & 1;
    const int mtile = (fw >> 1) & 3;
    const int ntile = fw >> 3;
    const int rlo  = lane & 15;
    const int khi  = lane >> 4;

    const unsigned short* aptr =
        h_cur + (size_t)(mtile * 16 + rlo) * Hh + ks * 1024 + khi * 8;
    const unsigned short* bptr =
        w_bf + (size_t)(ntile * 16 + rlo) * Hh + ks * 1024 + khi * 8;

    // epilogue operand prefetch (hides HBM latency under the MFMA loop)
    const int colg = ntile * 16 + rlo;
    const int row0 = mtile * 16 + khi * 4;
    float xp[4], nz[4];
    #pragma unroll
    for (int r = 0; r < 4; ++r) {
        xp[r] = out[(size_t)(row0 + r) * Tt * Hh + (size_t)t * Hh + colg];
        nz[r] = internal[(row0 + r) * Tt + t];
    }
    const float bh = b_hh[colg];

    f32x4 acc[4];
    #pragma unroll
    for (int q = 0; q < 4; ++q) acc[q] = (f32x4)0.f;

    #pragma unroll
    for (int it = 0; it < 32; ++it) {
        bf16x8 av = *(const bf16x8*)(aptr + it * 32);
        bf16x8 bv = *(const bf16x8*)(bptr + it * 32);
        acc[it & 3] = __builtin_amdgcn_mfma_f32_16x16x32_bf16(av, bv, acc[it & 3], 0, 0, 0);
    }
    f32x4 s4 = acc[0] + acc[1] + acc[2] + acc[3];

    if (ks) red[wid >> 1][lane] = s4;
    __syncthreads();
    if (!ks) {
        s4 += red[wid >> 1][lane];
        #pragma unroll
        for (int r = 0; r < 4; ++r) {
            const int b = row0 + r;
            const float g = tanhf(xp[r] + nz[r] + bh + s4[r]);
            out[(size_t)b * Tt * Hh + (size_t)t * Hh + colg] = g;
            h_nxt[(size_t)b * Hh + colg] = f2bf(g);
            if (t == Tt - 1)
                out[(size_t)Bb * Tt * Hh + (size_t)b * Hh + colg] = g;
        }
    }
}

// ---------------------------------------------------------------------------
extern "C" void kernel_launch(void* const* d_in, const int* in_sizes, int n_in,
                              void* d_out, int out_size, void* d_ws, size_t ws_size,
                              hipStream_t stream) {
    const float* input    = (const float*)d_in[0];
    const float* internal = (const float*)d_in[1];
    const float* w_ih     = (const float*)d_in[2];
    const float* w_hh     = (const float*)d_in[3];
    const float* b_ih     = (const float*)d_in[4];
    const float* b_hh     = (const float*)d_in[5];
    const float* h0       = (const float*)d_in[6];
    float* out = (float*)d_out;

    // ws layout: w_hh_bf [4M ushort] | w_ih_bf [2M ushort] | h_bf[2][64][2048]
    unsigned short* w_hh_bf = (unsigned short*)d_ws;
    unsigned short* w_ih_bf = w_hh_bf + (size_t)Hh * Hh;
    unsigned short* h_bf    = w_ih_bf + (size_t)Hh * Ii;

    hipLaunchKernelGGL(cvt_kernel, dim3((Hh * Hh) / 1024), dim3(256), 0, stream,
                       w_hh, w_hh_bf);
    hipLaunchKernelGGL(cvt_kernel, dim3((Hh * Ii) / 1024), dim3(256), 0, stream,
                       w_ih, w_ih_bf);
    hipLaunchKernelGGL(cvt_kernel, dim3((Bb * Hh) / 1024), dim3(256), 0, stream,
                       h0, h_bf);

    dim3 g1(Hh / 128, (Bb * Tt) / 128);   // 16 x 256
    hipLaunchKernelGGL(xproj_kernel, g1, dim3(256), 0, stream,
                       input, w_ih_bf, b_ih, out);

    for (int t = 0; t < Tt; ++t) {
        const unsigned short* h_cur = h_bf + (size_t)(t & 1) * Bb * Hh;
        unsigned short*       h_nxt = h_bf + (size_t)((t + 1) & 1) * Bb * Hh;
        hipLaunchKernelGGL(step_mfma, dim3(256), dim3(256), 0, stream,
                           w_hh_bf, h_cur, h_nxt, b_hh, internal, out, t);
    }
}